// Round 1
// baseline (152.229 us; speedup 1.0000x reference)
//
#include <hip/hip_runtime.h>
#include <cfloat>

#define BATCH 2048
#define DIM   256
#define NCLS  64
#define CHUNK 24   // rows of diffs staged in LDS per Gram tile (2 buffers + member list < 64KB)

// ---------------------------------------------------------------------------
// Kernel 1: per-sample argmax over logits [B,64] -> assign[b]
// first-occurrence-wins (strict >) to match jnp.argmax semantics.
// ---------------------------------------------------------------------------
__global__ __launch_bounds__(256) void argmax_kernel(const float* __restrict__ logits,
                                                     int* __restrict__ assign) {
    int b = blockIdx.x * blockDim.x + threadIdx.x;
    if (b >= BATCH) return;
    const float4* row = reinterpret_cast<const float4*>(logits + (size_t)b * NCLS);
    float best = -FLT_MAX;
    int bi = 0;
#pragma unroll
    for (int q = 0; q < NCLS / 4; ++q) {
        float4 v = row[q];
        if (v.x > best) { best = v.x; bi = 4 * q + 0; }
        if (v.y > best) { best = v.y; bi = 4 * q + 1; }
        if (v.z > best) { best = v.z; bi = 4 * q + 2; }
        if (v.w > best) { best = v.w; bi = 4 * q + 3; }
    }
    assign[b] = bi;
}

// ---------------------------------------------------------------------------
// Kernel 2: one block per cluster k.
//  - gather member indices (LDS list, order-invariant math)
//  - per-column tot/sq accumulation (thread t owns column t) during chunk load
//  - pairwise Gram sum S2all = sum_{i,j in k} (diff_i . diff_j)^2 via
//    wave-per-pair dot products on LDS-staged chunks
//  - finalize per-cluster penalty contributions -> partials[k], partials[K+k]
// ---------------------------------------------------------------------------
__global__ __launch_bounds__(256) void cluster_kernel(const float* __restrict__ emb,
                                                      const float* __restrict__ cen,
                                                      const int* __restrict__ assign,
                                                      float* __restrict__ partials) {
    const int k   = blockIdx.x;
    const int tid = threadIdx.x;
    const int wid  = tid >> 6;
    const int lane = tid & 63;

    __shared__ int   memb[BATCH];
    __shared__ int   cnt;
    __shared__ float XI[CHUNK][DIM];
    __shared__ float XJ[CHUNK][DIM];
    __shared__ float red[4][4];

    if (tid == 0) cnt = 0;
    __syncthreads();

    // gather members of cluster k (order is nondeterministic; math is permutation-invariant)
    for (int b = tid; b < BATCH; b += 256) {
        if (assign[b] == k) {
            int p = atomicAdd(&cnt, 1);
            memb[p] = b;
        }
    }
    __syncthreads();
    const int n = cnt;

    const float cen_t = cen[(size_t)k * DIM + tid];  // thread t owns column t
    float tot = 0.f;   // sum_b diff[b][t]
    float sqs = 0.f;   // sum_b diff[b][t]^2
    float s2  = 0.f;   // Gram partial (lane 0 of each wave accumulates)

    const int nc = (n + CHUNK - 1) / CHUNK;
    for (int ci = 0; ci < nc; ++ci) {
        const int ibase = ci * CHUNK;
        const int ni = min(CHUNK, n - ibase);

        __syncthreads();  // previous tile's compute done before overwriting XI
        for (int r = 0; r < ni; ++r) {
            float v = emb[(size_t)memb[ibase + r] * DIM + tid] - cen_t;
            XI[r][tid] = v;
            tot += v;                 // each member row loaded exactly once as XI
            sqs += v * v;
        }
        __syncthreads();

        for (int cj = ci; cj < nc; ++cj) {
            if (cj == ci) {
                // same-chunk pairs: i <= j, weight 1 on diagonal, 2 off
                const int npairs = ni * (ni + 1) / 2;
                for (int p = wid; p < npairs; p += 4) {
                    int jj = (int)((sqrtf(8.f * (float)p + 1.f) - 1.f) * 0.5f);
                    while ((jj + 1) * (jj + 2) / 2 <= p) ++jj;
                    while (jj * (jj + 1) / 2 > p) --jj;
                    const int i = p - jj * (jj + 1) / 2;
                    const int j = jj;
                    float dot = XI[i][lane]       * XI[j][lane]
                              + XI[i][lane + 64]  * XI[j][lane + 64]
                              + XI[i][lane + 128] * XI[j][lane + 128]
                              + XI[i][lane + 192] * XI[j][lane + 192];
#pragma unroll
                    for (int off = 32; off > 0; off >>= 1) dot += __shfl_xor(dot, off);
                    if (lane == 0) {
                        float w = (i == j) ? 1.f : 2.f;
                        s2 += w * dot * dot;
                    }
                }
            } else {
                const int jbase = cj * CHUNK;
                const int nj = min(CHUNK, n - jbase);
                __syncthreads();  // previous pair-compute done before overwriting XJ
                for (int r = 0; r < nj; ++r) {
                    XJ[r][tid] = emb[(size_t)memb[jbase + r] * DIM + tid] - cen_t;
                }
                __syncthreads();
                const int npairs = ni * nj;
                for (int p = wid; p < npairs; p += 4) {
                    const int i = p % ni;   // row in chunk ci (global idx < chunk cj rows)
                    const int j = p / ni;   // row in chunk cj
                    float dot = XI[i][lane]       * XJ[j][lane]
                              + XI[i][lane + 64]  * XJ[j][lane + 64]
                              + XI[i][lane + 128] * XJ[j][lane + 128]
                              + XI[i][lane + 192] * XJ[j][lane + 192];
#pragma unroll
                    for (int off = 32; off > 0; off >>= 1) dot += __shfl_xor(dot, off);
                    if (lane == 0) s2 += 2.f * dot * dot;  // i<j globally, always
                }
            }
        }
    }

    // ---- reductions over the 256 columns / 4 waves ----
    const float denom = (float)n + 1e-8f;
    float m1c = tot / denom;
    float v0 = m1c * m1c;   // -> M1
    float v1 = sqs;         // -> S1 (trace of m2sum)
    float v2 = sqs * sqs;   // -> S2d (diag Frobenius of m2sum)
    float v3 = s2;          // -> S2all (full Frobenius of m2sum)
#pragma unroll
    for (int off = 32; off > 0; off >>= 1) {
        v0 += __shfl_xor(v0, off);
        v1 += __shfl_xor(v1, off);
        v2 += __shfl_xor(v2, off);
        v3 += __shfl_xor(v3, off);
    }
    if (lane == 0) {
        red[wid][0] = v0; red[wid][1] = v1; red[wid][2] = v2; red[wid][3] = v3;
    }
    __syncthreads();
    if (tid == 0) {
        float M1 = 0.f, S1 = 0.f, S2d = 0.f, S2all = 0.f;
#pragma unroll
        for (int w = 0; w < 4; ++w) {
            M1 += red[w][0]; S1 += red[w][1]; S2d += red[w][2]; S2all += red[w][3];
        }
        const float cwn = (float)n / (float)BATCH;
        const float p1  = cwn * (1.f / (float)DIM) * M1;

        const float a  = 1.f / (2.f * (float)DIM);
        const float bb = 1.f / (2.f * (float)DIM * (float)(DIM - 1));
        const float sim_ab = cwn * a * (S1 / denom);
        const float sim_a  = sqrtf(cwn * ((a - bb) * S2d + bb * S2all) / (denom * denom) + 1e-6f);
        const float sim_b  = sqrtf(cwn * 0.5f + 1e-6f);   // sum_d w2[d,d] = D*a = 0.5
        const float sim    = sim_ab / (sim_a * sim_b + 1e-6f);

        partials[k]        = p1;
        partials[NCLS + k] = 1.f - sim;
    }
}

// ---------------------------------------------------------------------------
// Kernel 3: reduce 64 per-cluster partials -> scalar loss
// ---------------------------------------------------------------------------
__global__ __launch_bounds__(64) void final_kernel(const float* __restrict__ partials,
                                                   float* __restrict__ out) {
    int t = threadIdx.x;  // 64 threads = 1 wave
    float p1 = partials[t];
    float p2 = partials[NCLS + t];
#pragma unroll
    for (int off = 32; off > 0; off >>= 1) {
        p1 += __shfl_xor(p1, off);
        p2 += __shfl_xor(p2, off);
    }
    if (t == 0) out[0] = p1 + 0.05f * (p2 / (float)NCLS);
}

// ---------------------------------------------------------------------------
extern "C" void kernel_launch(void* const* d_in, const int* in_sizes, int n_in,
                              void* d_out, int out_size, void* d_ws, size_t ws_size,
                              hipStream_t stream) {
    const float* emb    = (const float*)d_in[0];  // [2048,256]
    const float* cen    = (const float*)d_in[1];  // [64,256]
    const float* logits = (const float*)d_in[2];  // [2048,64]
    float* out = (float*)d_out;

    int*   assign   = (int*)d_ws;                 // 2048 ints
    float* partials = (float*)d_ws + BATCH;       // 128 floats

    argmax_kernel <<<BATCH / 256, 256, 0, stream>>>(logits, assign);
    cluster_kernel<<<NCLS,        256, 0, stream>>>(emb, cen, assign, partials);
    final_kernel  <<<1,            64, 0, stream>>>(partials, out);
}

// Round 2
// 92.228 us; speedup vs baseline: 1.6506x; 1.6506x over previous
//
#include <hip/hip_runtime.h>
#include <cfloat>

#define BATCH 2048
#define DIM   256
#define NCLS  64
#define MAXS  56     // rows of diffs staged in LDS (avg cluster size ~32; global fallback above)
#define P_PER_K 4    // blocks per cluster
#define NWAVE   4    // waves per block (256 threads)
#define TOTW  (P_PER_K * NWAVE)

// workspace layout (floats after the 2048-int assign array)
//  g[0..63]    cnt (as float)
//  g[64..127]  M1
//  g[128..191] S1
//  g[192..255] S2d
//  g[256..319] S2all (atomic accumulated, zeroed in K1)

// ---------------------------------------------------------------------------
// K1: per-sample argmax over logits [B,64] -> assign[b]; block 0 zeroes S2all acc.
// first-occurrence-wins (strict >) to match jnp.argmax.
// ---------------------------------------------------------------------------
__global__ __launch_bounds__(256) void argmax_kernel(const float* __restrict__ logits,
                                                     int* __restrict__ assign,
                                                     float* __restrict__ g) {
    int b = blockIdx.x * blockDim.x + threadIdx.x;
    if (blockIdx.x == 0 && threadIdx.x < NCLS) g[256 + threadIdx.x] = 0.f;  // S2all acc
    if (b >= BATCH) return;
    const float4* row = reinterpret_cast<const float4*>(logits + (size_t)b * NCLS);
    float best = -FLT_MAX;
    int bi = 0;
#pragma unroll
    for (int q = 0; q < NCLS / 4; ++q) {
        float4 v = row[q];
        if (v.x > best) { best = v.x; bi = 4 * q + 0; }
        if (v.y > best) { best = v.y; bi = 4 * q + 1; }
        if (v.z > best) { best = v.z; bi = 4 * q + 2; }
        if (v.w > best) { best = v.w; bi = 4 * q + 3; }
    }
    assign[b] = bi;
}

// ---------------------------------------------------------------------------
// K2: P_PER_K blocks per cluster. Deterministic ballot-compaction member list
// (identical ordering across sibling blocks -> exact pair partition), LDS
// staging of diff rows, column stats on block p==0, pair-Gram strided over
// the cluster's 16 waves, one atomicAdd per block into S2all[k].
// ---------------------------------------------------------------------------
__global__ __launch_bounds__(256) void cluster_kernel(const float* __restrict__ emb,
                                                      const float* __restrict__ cen,
                                                      const int* __restrict__ assign,
                                                      float* __restrict__ g) {
    const int bid  = blockIdx.x;
    const int k    = bid / P_PER_K;
    const int p    = bid % P_PER_K;
    const int tid  = threadIdx.x;
    const int wid  = tid >> 6;
    const int lane = tid & 63;

    __shared__ unsigned short     memb[BATCH];
    __shared__ float              XS[MAXS][DIM];
    __shared__ float              cenL[DIM];
    __shared__ unsigned long long wmask[NWAVE];
    __shared__ float              wred[NWAVE][4];
    __shared__ float              s2red[NWAVE];

    cenL[tid] = cen[(size_t)k * DIM + tid];

    // ---- deterministic member compaction (sorted by b) ----
    int nrun = 0;
    for (int base = 0; base < BATCH; base += 256) {
        const int b = base + tid;
        const bool flag = (assign[b] == k);
        const unsigned long long m = __ballot(flag);
        if (lane == 0) wmask[wid] = m;
        __syncthreads();
        int off = 0;
        for (int w = 0; w < wid; ++w) off += __popcll(wmask[w]);
        if (flag) {
            int pin = __popcll(m & ((1ull << lane) - 1ull));
            memb[nrun + off + pin] = (unsigned short)b;
        }
        int tot = 0;
#pragma unroll
        for (int w = 0; w < NWAVE; ++w) tot += __popcll(wmask[w]);
        nrun += tot;
        __syncthreads();
    }
    const int n  = nrun;
    const int ns = (n < MAXS) ? n : MAXS;

    // ---- stage diff rows into LDS (coalesced 1KB row loads) ----
    for (int r = 0; r < ns; ++r)
        XS[r][tid] = emb[(size_t)memb[r] * DIM + tid] - cenL[tid];
    __syncthreads();

    // ---- column stats (block p==0 only): thread t owns column t ----
    if (p == 0) {
        const float denom = (float)n + 1e-8f;
        float tot = 0.f, sqs = 0.f;
        for (int r = 0; r < n; ++r) {
            float v = (r < MAXS) ? XS[r][tid]
                                 : emb[(size_t)memb[r] * DIM + tid] - cenL[tid];
            tot += v;
            sqs += v * v;
        }
        const float m1c = tot / denom;
        float v0 = m1c * m1c, v1 = sqs, v2 = sqs * sqs;
#pragma unroll
        for (int off = 32; off > 0; off >>= 1) {
            v0 += __shfl_xor(v0, off);
            v1 += __shfl_xor(v1, off);
            v2 += __shfl_xor(v2, off);
        }
        if (lane == 0) { wred[wid][0] = v0; wred[wid][1] = v1; wred[wid][2] = v2; }
        __syncthreads();
        if (tid == 0) {
            float M1 = 0.f, S1 = 0.f, S2d = 0.f;
#pragma unroll
            for (int w = 0; w < NWAVE; ++w) { M1 += wred[w][0]; S1 += wred[w][1]; S2d += wred[w][2]; }
            g[k]       = (float)n;
            g[64 + k]  = M1;
            g[128 + k] = S1;
            g[192 + k] = S2d;
        }
    }

    // ---- pair Gram: wave gw of TOTW handles rows j = gw, gw+TOTW, ... ----
    const int gw = p * NWAVE + wid;
    float s2 = 0.f;
    for (int j = gw; j < n; j += TOTW) {
        const float ja = (j < MAXS) ? XS[j][lane]       : emb[(size_t)memb[j] * DIM + lane]       - cenL[lane];
        const float jb = (j < MAXS) ? XS[j][lane + 64]  : emb[(size_t)memb[j] * DIM + lane + 64]  - cenL[lane + 64];
        const float jc = (j < MAXS) ? XS[j][lane + 128] : emb[(size_t)memb[j] * DIM + lane + 128] - cenL[lane + 128];
        const float jd = (j < MAXS) ? XS[j][lane + 192] : emb[(size_t)memb[j] * DIM + lane + 192] - cenL[lane + 192];
        for (int i = 0; i <= j; ++i) {
            float dot;
            if (i < MAXS) {
                dot = XS[i][lane]       * ja + XS[i][lane + 64]  * jb
                    + XS[i][lane + 128] * jc + XS[i][lane + 192] * jd;
            } else {
                const float* er = emb + (size_t)memb[i] * DIM;
                dot = (er[lane]       - cenL[lane])       * ja
                    + (er[lane + 64]  - cenL[lane + 64])  * jb
                    + (er[lane + 128] - cenL[lane + 128]) * jc
                    + (er[lane + 192] - cenL[lane + 192]) * jd;
            }
#pragma unroll
            for (int off = 32; off > 0; off >>= 1) dot += __shfl_xor(dot, off);
            s2 += ((i == j) ? 1.f : 2.f) * dot * dot;   // all lanes hold full dot
        }
    }
    if (lane == 0) s2red[wid] = s2;
    __syncthreads();
    if (tid == 0) {
        float bs = 0.f;
#pragma unroll
        for (int w = 0; w < NWAVE; ++w) bs += s2red[w];
        atomicAdd(&g[256 + k], bs);
    }
}

// ---------------------------------------------------------------------------
// K3: one wave, thread t = cluster t -> scalar loss
// ---------------------------------------------------------------------------
__global__ __launch_bounds__(64) void final_kernel(const float* __restrict__ g,
                                                   float* __restrict__ out) {
    const int t = threadIdx.x;
    const float n     = g[t];
    const float M1    = g[64 + t];
    const float S1    = g[128 + t];
    const float S2d   = g[192 + t];
    const float S2all = g[256 + t];

    const float denom = n + 1e-8f;
    const float cwn   = n / (float)BATCH;
    float p1 = cwn * (1.f / (float)DIM) * M1;

    const float a  = 1.f / (2.f * (float)DIM);
    const float bb = 1.f / (2.f * (float)DIM * (float)(DIM - 1));
    const float sim_ab = cwn * a * (S1 / denom);
    const float sim_a  = sqrtf(cwn * ((a - bb) * S2d + bb * S2all) / (denom * denom) + 1e-6f);
    const float sim_b  = sqrtf(cwn * 0.5f + 1e-6f);
    float p2 = 1.f - sim_ab / (sim_a * sim_b + 1e-6f);

#pragma unroll
    for (int off = 32; off > 0; off >>= 1) {
        p1 += __shfl_xor(p1, off);
        p2 += __shfl_xor(p2, off);
    }
    if (t == 0) out[0] = p1 + 0.05f * (p2 / (float)NCLS);
}

// ---------------------------------------------------------------------------
extern "C" void kernel_launch(void* const* d_in, const int* in_sizes, int n_in,
                              void* d_out, int out_size, void* d_ws, size_t ws_size,
                              hipStream_t stream) {
    const float* emb    = (const float*)d_in[0];  // [2048,256]
    const float* cen    = (const float*)d_in[1];  // [64,256]
    const float* logits = (const float*)d_in[2];  // [2048,64]
    float* out = (float*)d_out;

    int*   assign = (int*)d_ws;                   // 2048 ints
    float* g      = (float*)d_ws + BATCH;         // 320 floats

    argmax_kernel <<<BATCH / 256,     256, 0, stream>>>(logits, assign, g);
    cluster_kernel<<<NCLS * P_PER_K,  256, 0, stream>>>(emb, cen, assign, g);
    final_kernel  <<<1,                64, 0, stream>>>(g, out);
}

// Round 3
// 84.488 us; speedup vs baseline: 1.8018x; 1.0916x over previous
//
#include <hip/hip_runtime.h>
#include <cfloat>

#define BATCH 2048
#define DIM   256
#define NCLS  64
#define MAXS  64     // rows held in LDS fast path (cluster sizes ~32±6; generic fallback above)
#define XROW  260    // padded LDS row stride in words (260%32==4 -> b128 reads at LDS BW floor)
#define P_PER_K 4    // blocks per cluster
#define NWAVE   4
#define TOTW  (P_PER_K * NWAVE)

// d_ws layout (bytes):
//   0       cntG[64]  (int)   per-cluster member counts   [zeroed via hipMemsetAsync]
//   1024    memG[64][2048] (int) per-cluster member lists (append order nondeterministic;
//                                 all math is permutation-invariant and all sibling blocks
//                                 read the same list -> exact pair partition)
//   1<<20   g[448] (float): M1[64] | S1[64] | S2d[64] | S2allPart[64*4]

// ---------------------------------------------------------------------------
// K1: wave-per-row argmax (first-occurrence tie-break) + atomic append to
// the per-cluster member list. 256 blocks x 256 thr; 2 rows per wave.
// ---------------------------------------------------------------------------
__global__ __launch_bounds__(256) void argmax_kernel(const float* __restrict__ logits,
                                                     int* __restrict__ cntG,
                                                     int* __restrict__ memG) {
    const int wid = threadIdx.x >> 6, lane = threadIdx.x & 63;
#pragma unroll
    for (int q = 0; q < 2; ++q) {
        const int row = blockIdx.x * 8 + wid * 2 + q;
        float v  = logits[row * NCLS + lane];
        int  idx = lane;
#pragma unroll
        for (int off = 32; off > 0; off >>= 1) {
            const float vo = __shfl_xor(v, off);
            const int   io = __shfl_xor(idx, off);
            if (vo > v || (vo == v && io < idx)) { v = vo; idx = io; }
        }
        if (lane == 0) {
            const int slot = atomicAdd(&cntG[idx], 1);
            memG[idx * BATCH + slot] = row;
        }
    }
}

// ---------------------------------------------------------------------------
// K2: P_PER_K blocks per cluster. LDS-staged diff rows; column stats on p==0;
// ordered-pair Gram with lane-parallel dots (no per-dot shuffles).
// ---------------------------------------------------------------------------
__global__ __launch_bounds__(256) void cluster_kernel(const float* __restrict__ emb,
                                                      const float* __restrict__ cen,
                                                      const int* __restrict__ cntG,
                                                      const int* __restrict__ memG,
                                                      float* __restrict__ g) {
    const int bid = blockIdx.x;
    const int k = bid >> 2, p = bid & 3;
    const int tid = threadIdx.x, wid = tid >> 6, lane = tid & 63;
    const int gw = p * NWAVE + wid;

    __shared__ float XS[MAXS * XROW];
    __shared__ float cenL[DIM];
    __shared__ int   membL[MAXS];
    __shared__ float wred[NWAVE][3];
    __shared__ float s2red[NWAVE];

    const int  n  = cntG[k];
    const int* mk = memG + k * BATCH;
    cenL[tid] = cen[k * DIM + tid];
    if (tid < MAXS && tid < n) membL[tid] = mk[tid];
    __syncthreads();

    const float denom = (float)n + 1e-8f;
    float s2 = 0.f;

    if (n <= MAXS) {
        // ---- stage diff rows: one row per wave per iteration, float4 per lane ----
        const int c4 = (tid & 63) << 2;
        for (int r0 = 0; r0 < n; r0 += NWAVE) {
            const int r = r0 + wid;
            if (r < n) {
                const float4 e  = *(const float4*)(emb + (size_t)membL[r] * DIM + c4);
                const float4 cc = *(const float4*)(&cenL[c4]);
                float4 v; v.x = e.x - cc.x; v.y = e.y - cc.y; v.z = e.z - cc.z; v.w = e.w - cc.w;
                *(float4*)(&XS[r * XROW + c4]) = v;
            }
        }
        __syncthreads();

        // ---- column stats (p==0): thread t owns column t ----
        if (p == 0) {
            float tot = 0.f, sqs = 0.f;
            for (int r = 0; r < n; ++r) {
                const float v = XS[r * XROW + tid];
                tot += v; sqs += v * v;
            }
            const float m1c = tot / denom;
            float v0 = m1c * m1c, v1 = sqs, v2 = sqs * sqs;
#pragma unroll
            for (int off = 32; off > 0; off >>= 1) {
                v0 += __shfl_xor(v0, off);
                v1 += __shfl_xor(v1, off);
                v2 += __shfl_xor(v2, off);
            }
            if (lane == 0) { wred[wid][0] = v0; wred[wid][1] = v1; wred[wid][2] = v2; }
            __syncthreads();
            if (tid == 0) {
                float M1 = 0.f, S1 = 0.f, S2d = 0.f;
#pragma unroll
                for (int w = 0; w < NWAVE; ++w) { M1 += wred[w][0]; S1 += wred[w][1]; S2d += wred[w][2]; }
                g[k]       = M1;
                g[64 + k]  = S1;
                g[128 + k] = S2d;
            }
        }

        // ---- ordered-pair Gram: lane = row i, wave gw strides j ----
        const float* xi = &XS[lane * XROW];
        for (int j = gw; j < n; j += TOTW) {
            const float* xj = &XS[j * XROW];   // wave-uniform -> LDS broadcast
            float ax = 0.f, ay = 0.f, az = 0.f, aw = 0.f;
            for (int d = 0; d < DIM; d += 4) {
                const float4 vi = *(const float4*)(xi + d);
                const float4 vj = *(const float4*)(xj + d);
                ax += vi.x * vj.x; ay += vi.y * vj.y;
                az += vi.z * vj.z; aw += vi.w * vj.w;
            }
            const float dot = (ax + ay) + (az + aw);
            if (lane < n) s2 += dot * dot;
        }
    } else {
        // ---- generic fallback (n > MAXS): correct for any n, never hot ----
        if (p == 0) {
            float tot = 0.f, sqs = 0.f;
            for (int r = 0; r < n; ++r) {
                const float v = emb[(size_t)mk[r] * DIM + tid] - cenL[tid];
                tot += v; sqs += v * v;
            }
            const float m1c = tot / denom;
            float v0 = m1c * m1c, v1 = sqs, v2 = sqs * sqs;
#pragma unroll
            for (int off = 32; off > 0; off >>= 1) {
                v0 += __shfl_xor(v0, off);
                v1 += __shfl_xor(v1, off);
                v2 += __shfl_xor(v2, off);
            }
            if (lane == 0) { wred[wid][0] = v0; wred[wid][1] = v1; wred[wid][2] = v2; }
            __syncthreads();
            if (tid == 0) {
                float M1 = 0.f, S1 = 0.f, S2d = 0.f;
#pragma unroll
                for (int w = 0; w < NWAVE; ++w) { M1 += wred[w][0]; S1 += wred[w][1]; S2d += wred[w][2]; }
                g[k]       = M1;
                g[64 + k]  = S1;
                g[128 + k] = S2d;
            }
        }
        for (int j = gw; j < n; j += TOTW) {
            const float* ej = emb + (size_t)mk[j] * DIM;   // wave-uniform
            for (int ib = 0; ib < n; ib += 64) {
                const int i = ib + lane;
                if (i < n) {
                    const float* ei = emb + (size_t)mk[i] * DIM;
                    float dot = 0.f;
                    for (int d = 0; d < DIM; d += 4) {
                        const float4 a = *(const float4*)(ei + d);
                        const float4 b = *(const float4*)(ej + d);
                        const float4 c = *(const float4*)(&cenL[d]);
                        dot += (a.x - c.x) * (b.x - c.x) + (a.y - c.y) * (b.y - c.y)
                             + (a.z - c.z) * (b.z - c.z) + (a.w - c.w) * (b.w - c.w);
                    }
                    s2 += dot * dot;
                }
            }
        }
    }

    // ---- block-sum of s2 -> per-block partial (written exactly once, no init needed) ----
#pragma unroll
    for (int off = 32; off > 0; off >>= 1) s2 += __shfl_xor(s2, off);
    if (lane == 0) s2red[wid] = s2;
    __syncthreads();
    if (tid == 0) {
        float bs = 0.f;
#pragma unroll
        for (int w = 0; w < NWAVE; ++w) bs += s2red[w];
        g[192 + k * P_PER_K + p] = bs;
    }
}

// ---------------------------------------------------------------------------
// K3: one wave, thread t = cluster t -> scalar loss
// ---------------------------------------------------------------------------
__global__ __launch_bounds__(64) void final_kernel(const int* __restrict__ cntG,
                                                   const float* __restrict__ g,
                                                   float* __restrict__ out) {
    const int t = threadIdx.x;
    const float n     = (float)cntG[t];
    const float M1    = g[t];
    const float S1    = g[64 + t];
    const float S2d   = g[128 + t];
    const float S2all = g[192 + 4 * t] + g[192 + 4 * t + 1]
                      + g[192 + 4 * t + 2] + g[192 + 4 * t + 3];

    const float denom = n + 1e-8f;
    const float cwn   = n / (float)BATCH;
    float p1 = cwn * (1.f / (float)DIM) * M1;

    const float a  = 1.f / (2.f * (float)DIM);
    const float bb = 1.f / (2.f * (float)DIM * (float)(DIM - 1));
    const float sim_ab = cwn * a * (S1 / denom);
    const float sim_a  = sqrtf(cwn * ((a - bb) * S2d + bb * S2all) / (denom * denom) + 1e-6f);
    const float sim_b  = sqrtf(cwn * 0.5f + 1e-6f);
    float p2 = 1.f - sim_ab / (sim_a * sim_b + 1e-6f);

#pragma unroll
    for (int off = 32; off > 0; off >>= 1) {
        p1 += __shfl_xor(p1, off);
        p2 += __shfl_xor(p2, off);
    }
    if (t == 0) out[0] = p1 + 0.05f * (p2 / (float)NCLS);
}

// ---------------------------------------------------------------------------
extern "C" void kernel_launch(void* const* d_in, const int* in_sizes, int n_in,
                              void* d_out, int out_size, void* d_ws, size_t ws_size,
                              hipStream_t stream) {
    const float* emb    = (const float*)d_in[0];  // [2048,256]
    const float* cen    = (const float*)d_in[1];  // [64,256]
    const float* logits = (const float*)d_in[2];  // [2048,64]
    float* out = (float*)d_out;

    int*   cntG = (int*)d_ws;                            // 64 ints @ 0
    int*   memG = (int*)((char*)d_ws + 1024);            // 64*2048 ints
    float* g    = (float*)((char*)d_ws + (1 << 20));     // 448 floats

    hipMemsetAsync(d_ws, 0, 256, stream);                // zero cntG only
    argmax_kernel <<<BATCH / 8,       256, 0, stream>>>(logits, cntG, memG);
    cluster_kernel<<<NCLS * P_PER_K,  256, 0, stream>>>(emb, cen, cntG, memG, g);
    final_kernel  <<<1,                64, 0, stream>>>(cntG, g, out);
}

// Round 10
// 76.819 us; speedup vs baseline: 1.9817x; 1.0998x over previous
//
#include <hip/hip_runtime.h>
#include <cfloat>

#define BATCH 2048
#define DIM   256
#define NCLS  64
#define MAXS  64     // rows held in LDS fast path (cluster sizes ~32±6; generic fallback above)
#define XROW  260    // padded LDS row stride in words (measured: 0 LDS bank conflicts in R3)
#define P_PER_K 4    // sibling blocks per cluster
#define NWAVE   4
#define TOTW  (P_PER_K * NWAVE)
#define SEG   (BATCH / NWAVE)   // 512 assign rows scanned per wave in compaction

// d_ws layout:
//   0     assign[2048] (int)   fully rewritten by K1 every launch
//   8192  g[512] (float): M1[64] | S1[64] | S2d[64] | S2allPart[64*4] | n[64]
// No memset needed: every g slot is written unconditionally every launch; no
// index ever derives from workspace contents that weren't written this launch.

// ---------------------------------------------------------------------------
// K1: wave-per-row argmax (first-occurrence tie-break) -> assign[row]. No atomics.
// ---------------------------------------------------------------------------
__global__ __launch_bounds__(256) void argmax_kernel(const float* __restrict__ logits,
                                                     int* __restrict__ assign) {
    const int wid = threadIdx.x >> 6, lane = threadIdx.x & 63;
#pragma unroll
    for (int q = 0; q < 2; ++q) {
        const int row = blockIdx.x * 8 + wid * 2 + q;
        float v  = logits[row * NCLS + lane];
        int  idx = lane;
#pragma unroll
        for (int off = 32; off > 0; off >>= 1) {
            const float vo = __shfl_xor(v, off);
            const int   io = __shfl_xor(idx, off);
            if (vo > v || (vo == v && io < idx)) { v = vo; idx = io; }
        }
        if (lane == 0) assign[row] = idx;
    }
}

// ---------------------------------------------------------------------------
// K2: P_PER_K sibling blocks per cluster. Each block independently builds the
// SAME deterministic member list (per-wave segmented ballot compaction — a pure
// function of assign[], no atomics), stages diff rows in LDS, computes column
// stats (p==0 block), and the pairwise-Gram partial (all blocks, wave-strided).
// ---------------------------------------------------------------------------
__global__ __launch_bounds__(256) void cluster_kernel(const float* __restrict__ emb,
                                                      const float* __restrict__ cen,
                                                      const int* __restrict__ assign,
                                                      float* __restrict__ g) {
    const int bid = blockIdx.x;
    const int k = bid >> 2, p = bid & 3;
    const int tid = threadIdx.x, wid = tid >> 6, lane = tid & 63;
    const int gw = p * NWAVE + wid;

    __shared__ float          XS[MAXS * XROW];
    __shared__ float          cenL[DIM];
    __shared__ unsigned short membSeg[BATCH];   // per-wave segments (wave w: [w*SEG, ...))
    __shared__ unsigned short memb[BATCH];      // concatenated deterministic member list
    __shared__ int            cntSeg[NWAVE];
    __shared__ float          wred[NWAVE][3];
    __shared__ float          s2red[NWAVE];

    cenL[tid] = cen[k * DIM + tid];

    // ---- deterministic compaction: wave w scans rows [w*SEG, (w+1)*SEG) ----
    {
        const int base = wid * SEG;
        int wcnt = 0;
        for (int t = 0; t < SEG / 64; ++t) {              // 8 ballots, no barriers
            const int b = base + t * 64 + lane;
            const bool f = (assign[b] == k);
            const unsigned long long m = __ballot(f);
            if (f) {
                const int pos = __popcll(m & ((1ull << lane) - 1ull));
                membSeg[base + wcnt + pos] = (unsigned short)b;
            }
            wcnt += __popcll(m);
        }
        if (lane == 0) cntSeg[wid] = wcnt;
    }
    __syncthreads();

    int offs[NWAVE + 1];
    offs[0] = 0;
#pragma unroll
    for (int w = 0; w < NWAVE; ++w) offs[w + 1] = offs[w] + cntSeg[w];
    const int n = offs[NWAVE];
#pragma unroll
    for (int w = 0; w < NWAVE; ++w)
        for (int i = tid; i < cntSeg[w]; i += 256)
            memb[offs[w] + i] = membSeg[w * SEG + i];
    __syncthreads();

    const float denom = (float)n + 1e-8f;
    float s2 = 0.f;

    if (n <= MAXS) {
        // ---- stage diff rows: one row per wave per iteration, float4 per lane ----
        const int c4 = lane << 2;
        for (int r0 = 0; r0 < n; r0 += NWAVE) {
            const int r = r0 + wid;
            if (r < n) {
                const float4 e  = *(const float4*)(emb + (size_t)memb[r] * DIM + c4);
                const float4 cc = *(const float4*)(&cenL[c4]);
                float4 v; v.x = e.x - cc.x; v.y = e.y - cc.y; v.z = e.z - cc.z; v.w = e.w - cc.w;
                *(float4*)(&XS[r * XROW + c4]) = v;
            }
        }
        __syncthreads();

        // ---- column stats (p==0): thread t owns column t ----
        if (p == 0) {
            float tot = 0.f, sqs = 0.f;
            for (int r = 0; r < n; ++r) {
                const float v = XS[r * XROW + tid];
                tot += v; sqs += v * v;
            }
            const float m1c = tot / denom;
            float v0 = m1c * m1c, v1 = sqs, v2 = sqs * sqs;
#pragma unroll
            for (int off = 32; off > 0; off >>= 1) {
                v0 += __shfl_xor(v0, off);
                v1 += __shfl_xor(v1, off);
                v2 += __shfl_xor(v2, off);
            }
            if (lane == 0) { wred[wid][0] = v0; wred[wid][1] = v1; wred[wid][2] = v2; }
            __syncthreads();
            if (tid == 0) {
                float M1 = 0.f, S1 = 0.f, S2d = 0.f;
#pragma unroll
                for (int w = 0; w < NWAVE; ++w) { M1 += wred[w][0]; S1 += wred[w][1]; S2d += wred[w][2]; }
                g[k]       = M1;
                g[64 + k]  = S1;
                g[128 + k] = S2d;
                g[448 + k] = (float)n;
            }
        }

        // ---- ordered-pair Gram: lane = row i, wave gw strides j; sum over ALL
        //      (i,j) ordered pairs = Frobenius^2 of the Gram matrix = S2all ----
        const float* xi = &XS[lane * XROW];
        for (int j = gw; j < n; j += TOTW) {
            const float* xj = &XS[j * XROW];   // wave-uniform -> LDS broadcast
            float ax = 0.f, ay = 0.f, az = 0.f, aw = 0.f;
            for (int d = 0; d < DIM; d += 4) {
                const float4 vi = *(const float4*)(xi + d);
                const float4 vj = *(const float4*)(xj + d);
                ax += vi.x * vj.x; ay += vi.y * vj.y;
                az += vi.z * vj.z; aw += vi.w * vj.w;
            }
            const float dot = (ax + ay) + (az + aw);
            if (lane < n) s2 += dot * dot;
        }
    } else {
        // ---- generic fallback (n > MAXS): correct for any n, never hot ----
        if (p == 0) {
            float tot = 0.f, sqs = 0.f;
            for (int r = 0; r < n; ++r) {
                const float v = emb[(size_t)memb[r] * DIM + tid] - cenL[tid];
                tot += v; sqs += v * v;
            }
            const float m1c = tot / denom;
            float v0 = m1c * m1c, v1 = sqs, v2 = sqs * sqs;
#pragma unroll
            for (int off = 32; off > 0; off >>= 1) {
                v0 += __shfl_xor(v0, off);
                v1 += __shfl_xor(v1, off);
                v2 += __shfl_xor(v2, off);
            }
            if (lane == 0) { wred[wid][0] = v0; wred[wid][1] = v1; wred[wid][2] = v2; }
            __syncthreads();
            if (tid == 0) {
                float M1 = 0.f, S1 = 0.f, S2d = 0.f;
#pragma unroll
                for (int w = 0; w < NWAVE; ++w) { M1 += wred[w][0]; S1 += wred[w][1]; S2d += wred[w][2]; }
                g[k]       = M1;
                g[64 + k]  = S1;
                g[128 + k] = S2d;
                g[448 + k] = (float)n;
            }
        }
        for (int j = gw; j < n; j += TOTW) {
            const float* ej = emb + (size_t)memb[j] * DIM;   // wave-uniform
            for (int ib = 0; ib < n; ib += 64) {
                const int i = ib + lane;
                if (i < n) {
                    const float* ei = emb + (size_t)memb[i] * DIM;
                    float dot = 0.f;
                    for (int d = 0; d < DIM; d += 4) {
                        const float4 a = *(const float4*)(ei + d);
                        const float4 b = *(const float4*)(ej + d);
                        const float4 c = *(const float4*)(&cenL[d]);
                        dot += (a.x - c.x) * (b.x - c.x) + (a.y - c.y) * (b.y - c.y)
                             + (a.z - c.z) * (b.z - c.z) + (a.w - c.w) * (b.w - c.w);
                    }
                    s2 += dot * dot;
                }
            }
        }
    }

    // ---- block-sum of s2 -> per-block partial (plain store, no init needed) ----
#pragma unroll
    for (int off = 32; off > 0; off >>= 1) s2 += __shfl_xor(s2, off);
    if (lane == 0) s2red[wid] = s2;
    __syncthreads();
    if (tid == 0) {
        float bs = 0.f;
#pragma unroll
        for (int w = 0; w < NWAVE; ++w) bs += s2red[w];
        g[192 + k * P_PER_K + p] = bs;
    }
}

// ---------------------------------------------------------------------------
// K3: one wave, thread t = cluster t -> scalar loss
// ---------------------------------------------------------------------------
__global__ __launch_bounds__(64) void final_kernel(const float* __restrict__ g,
                                                   float* __restrict__ out) {
    const int t = threadIdx.x;
    const float n     = g[448 + t];
    const float M1    = g[t];
    const float S1    = g[64 + t];
    const float S2d   = g[128 + t];
    const float S2all = g[192 + 4 * t] + g[192 + 4 * t + 1]
                      + g[192 + 4 * t + 2] + g[192 + 4 * t + 3];

    const float denom = n + 1e-8f;
    const float cwn   = n / (float)BATCH;
    float p1 = cwn * (1.f / (float)DIM) * M1;

    const float a  = 1.f / (2.f * (float)DIM);
    const float bb = 1.f / (2.f * (float)DIM * (float)(DIM - 1));
    const float sim_ab = cwn * a * (S1 / denom);
    const float sim_a  = sqrtf(cwn * ((a - bb) * S2d + bb * S2all) / (denom * denom) + 1e-6f);
    const float sim_b  = sqrtf(cwn * 0.5f + 1e-6f);
    float p2 = 1.f - sim_ab / (sim_a * sim_b + 1e-6f);

#pragma unroll
    for (int off = 32; off > 0; off >>= 1) {
        p1 += __shfl_xor(p1, off);
        p2 += __shfl_xor(p2, off);
    }
    if (t == 0) out[0] = p1 + 0.05f * (p2 / (float)NCLS);
}

// ---------------------------------------------------------------------------
extern "C" void kernel_launch(void* const* d_in, const int* in_sizes, int n_in,
                              void* d_out, int out_size, void* d_ws, size_t ws_size,
                              hipStream_t stream) {
    const float* emb    = (const float*)d_in[0];  // [2048,256]
    const float* cen    = (const float*)d_in[1];  // [64,256]
    const float* logits = (const float*)d_in[2];  // [2048,64]
    float* out = (float*)d_out;

    int*   assign = (int*)d_ws;                        // 2048 ints @ 0
    float* g      = (float*)((char*)d_ws + 8192);      // 512 floats

    argmax_kernel <<<BATCH / 8,       256, 0, stream>>>(logits, assign);
    cluster_kernel<<<NCLS * P_PER_K,  256, 0, stream>>>(emb, cen, assign, g);
    final_kernel  <<<1,                64, 0, stream>>>(g, out);
}